// Round 9
// baseline (2512.934 us; speedup 1.0000x reference)
//
#include <hip/hip_runtime.h>
#include <hip/hip_bf16.h>

#define B_   8
#define T_   12
#define CIN  16
#define HD   96
#define COUT 8
#define CE   112
#define CD   104
#define HW   4096
#define WIMG 64

typedef __hip_bfloat16 bf16;
typedef __attribute__((ext_vector_type(8))) short bf16x8;   // 8 bf16 (4 VGPRs)
typedef __attribute__((ext_vector_type(16))) float f32x16;  // MFMA 32x32 C/D

__device__ __forceinline__ float b2f(bf16 v) { return __bfloat162float(v); }
__device__ __forceinline__ float sigmf_(float x) { return 1.0f / (1.0f + __expf(-x)); }
__device__ __forceinline__ float tanhf_(float x) { return 2.0f / (1.0f + __expf(-2.0f * x)) - 1.0f; }

__device__ __forceinline__ float ldin(const void* p, long i, int f32) {
    return f32 ? ((const float*)p)[i] : b2f(((const bf16*)p)[i]);
}
__device__ __forceinline__ short f2bs(float v) {
    __hip_bfloat16 hv = __float2bfloat16(v);
    return *reinterpret_cast<short*>(&hv);
}

// ---------------------------------------------------------------------------
// manual grid barrier: monotonic arrival counter, device-scope atomics.
// Safe by capacity: grid=256 blocks, 1 block/CU min occupancy -> all resident.
// ---------------------------------------------------------------------------
__device__ __forceinline__ void gridbar(int* bar, int target) {
    __syncthreads();
    if (threadIdx.x == 0) {
        __threadfence();                       // release block's writes
        atomicAdd(bar, 1);                     // device-scope arrival
        while (__hip_atomic_load(bar, __ATOMIC_RELAXED,
                                 __HIP_MEMORY_SCOPE_AGENT) < target)
            __builtin_amdgcn_s_sleep(2);
    }
    __syncthreads();
    __threadfence();                           // acquire (invalidate caches)
}

// ---------------------------------------------------------------------------
// detect: fp32 vs bf16 input dtype; also zero the grid barrier counter
// ---------------------------------------------------------------------------
__global__ void detect_k(const void* w, int* flag, int* bar) {
    if (threadIdx.x == 0 && blockIdx.x == 0) {
        const unsigned short* u = (const unsigned short*)w;
        int bad = 0;
        for (int i = 0; i < 64; i++) {
            unsigned short v = u[i];
            unsigned e = (v >> 7) & 0xFF;
            if (!(v == 0 || (e >= 90 && e <= 128))) bad++;
        }
        *flag = (bad > 8) ? 1 : 0;
        *bar = 0;
    }
}

// ---------------------------------------------------------------------------
// prep: convert all recurrent-loop weights (bf16 or fp32) -> fp32 workspace
// ---------------------------------------------------------------------------
__global__ void prep_k(
    const void* p0, const void* p1, const void* p2, const void* p3,
    const void* p4, const void* p5, const void* p6, const void* p7,
    const void* p8, const void* p9, const void* p10, const void* p11,
    const void* p12, const void* p13, const void* p14, const void* p15,
    float* __restrict__ dst, const int* __restrict__ flag)
{
    const int f32 = *flag;
    const void* srcs[16] = {p0,p1,p2,p3,p4,p5,p6,p7,p8,p9,p10,p11,p12,p13,p14,p15};
    const int sizes[16] = {10752,10752,10752,10752, 96,96,96,96,
                           89856,89856,89856, 96,96,96, 9984, 96};
    int i = blockIdx.x * blockDim.x + threadIdx.x;
    float* d = dst;
    #pragma unroll 1
    for (int s = 0; s < 16; s++) {
        if (i < sizes[s]) { d[i] = ldin(srcs[s], i, f32); return; }
        i -= sizes[s];
        d += sizes[s];
    }
}

// ---------------------------------------------------------------------------
// combine: fold output head conv(oK)+ob then linear(lW)+lb into one conv
// ---------------------------------------------------------------------------
__global__ void combine_k(const void* __restrict__ oK, const void* __restrict__ obv,
                          const void* __restrict__ lW, const void* __restrict__ lb,
                          float* __restrict__ K2, float* __restrict__ b2,
                          const int* __restrict__ flag)
{
    const int f32 = *flag;
    int i = blockIdx.x * blockDim.x + threadIdx.x;
    if (i < HD * 9) {
        float acc[8] = {0,0,0,0,0,0,0,0};
        for (int cd = 0; cd < CD; cd++) {
            float kv = ldin(oK, cd * (HD * 9) + i, f32);
            #pragma unroll
            for (int o = 0; o < 8; o++)
                acc[o] = fmaf(kv, ldin(lW, cd * COUT + o, f32), acc[o]);
        }
        #pragma unroll
        for (int o = 0; o < 8; o++) K2[i * 8 + o] = acc[o];
    }
    if (i < COUT) {
        float a = ldin(lb, i, f32);
        for (int cd = 0; cd < CD; cd++)
            a = fmaf(ldin(obv, cd, f32), ldin(lW, cd * COUT + i, f32), a);
        b2[i] = a;
    }
}

// ---------------------------------------------------------------------------
// repack decoder gate weights into MFMA A-fragment order:
// WtA[((tap*7 + k0)*12 + mt)*64 + lane]*8+j ; m=mt*32+(lane&31);
// gate=m/96 (f,i,g,o), d=m%96; ch = k0*16+(lane>>5)*8+j (0..111, >=104 pad)
// rec layout: ch 0..7 = x, 8..103 = h
// ---------------------------------------------------------------------------
__global__ void repack_mfma_k(const float* __restrict__ Kf, const float* __restrict__ Ki,
                              const float* __restrict__ Kc, const float* __restrict__ dWof,
                              short* __restrict__ WtA)
{
    int lin = blockIdx.x * 256 + threadIdx.x;
    if (lin >= 9 * 7 * 12 * 64) return;
    int lane = lin & 63;
    int rest = lin >> 6;
    int mt  = rest % 12;
    int k07 = rest / 12;
    int k0  = k07 % 7;
    int tap = k07 / 7;
    int m = mt * 32 + (lane & 31);
    int gate = m / 96, d = m % 96;
    int chb = k0 * 16 + (lane >> 5) * 8;
    #pragma unroll
    for (int j = 0; j < 8; j++) {
        int ch = chb + j;
        float v = 0.f;
        if (ch < 104) {
            if (gate == 0)      v = Kf[((size_t)d * CD + ch) * 9 + tap];
            else if (gate == 1) v = Ki[((size_t)d * CD + ch) * 9 + tap];
            else if (gate == 2) v = Kc[((size_t)d * CD + ch) * 9 + tap];
            else                v = (tap == 4) ? dWof[ch * HD + d] : 0.f;
        }
        WtA[(size_t)lin * 8 + j] = f2bs(v);
    }
}

// ---------------------------------------------------------------------------
// repack encoder weights: EW[((k0*12 + mt)*64 + lane)*8+j]
// rec layout: ch 0..15 = x, 16..111 = h (matches eW rows directly)
// ---------------------------------------------------------------------------
__global__ void repack_enc_k(const float* __restrict__ Wf, const float* __restrict__ Wi,
                             const float* __restrict__ Wc, const float* __restrict__ Wo,
                             short* __restrict__ EW)
{
    int lin = blockIdx.x * 256 + threadIdx.x;
    if (lin >= 7 * 12 * 64) return;
    int lane = lin & 63;
    int rest = lin >> 6;
    int mt = rest % 12;
    int k0 = rest / 12;
    int m = mt * 32 + (lane & 31);
    int gate = m / 96, d = m % 96;
    int chb = k0 * 16 + (lane >> 5) * 8;
    const float* W = (gate == 0) ? Wf : (gate == 1) ? Wi : (gate == 2) ? Wc : Wo;
    #pragma unroll
    for (int j = 0; j < 8; j++)
        EW[(size_t)lin * 8 + j] = f2bs(W[(chb + j) * HD + d]);
}

// ---------------------------------------------------------------------------
// repack combined out-head conv K2 into one MFMA m-tile (rows 0..7 = out ch):
// K2A[((tap*7 + k0)*64 + lane)*8+j]; k = k0*16+(lane>>5)*8+j -> h ch c = k-8
// ---------------------------------------------------------------------------
__global__ void repack_k2a_k(const float* __restrict__ K2, short* __restrict__ K2A)
{
    int lin = blockIdx.x * 256 + threadIdx.x;
    if (lin >= 9 * 7 * 64) return;
    int lane = lin & 63;
    int rest = lin >> 6;
    int k0 = rest % 7;
    int tap = rest / 7;
    int m = lane & 31;
    int kb = k0 * 16 + (lane >> 5) * 8;
    #pragma unroll
    for (int j = 0; j < 8; j++) {
        int c = kb + j - 8;
        float v = (m < 8 && c >= 0 && c < 96) ? K2[(c * 9 + tap) * 8 + m] : 0.f;
        K2A[(size_t)lin * 8 + j] = f2bs(v);
    }
}

// ---------------------------------------------------------------------------
// persistent kernel: whole enc+dec recurrence. grid 256 = 32 bands x 8 batch,
// block 256 = 4 waves, 1 block/CU. c in registers (48 f32/thread). enc h in
// LDS (zero grid syncs). dec: own 2 rows persist in LDS; halo rows via
// ping-pong global + manual grid barrier. out head fused as extra m-tile.
// k0 loops FULLY UNROLLED: 1 wave/SIMD means no TLP -> all latency hiding
// must come from ILP; unrolling exposes the independent A-frag loads.
// ---------------------------------------------------------------------------
__global__ void __launch_bounds__(256, 1) net_k(
    const void* __restrict__ xe, const void* __restrict__ xd,
    short* __restrict__ hPA, short* __restrict__ hPB,
    void* __restrict__ out,
    const short* __restrict__ EW, const short* __restrict__ WtA,
    const short* __restrict__ K2A,
    const float* __restrict__ ebf, const float* __restrict__ ebi,
    const float* __restrict__ ebc, const float* __restrict__ ebo,
    const float* __restrict__ dbf, const float* __restrict__ dbi,
    const float* __restrict__ dbc, const float* __restrict__ dbo,
    const float* __restrict__ b2, const int* __restrict__ flag,
    int* __restrict__ bar)
{
    __shared__ short lds[4 * 66 * 120];       // 63,360 B
    const int f32 = *flag;
    const int tid  = threadIdx.x;
    const int b    = blockIdx.x & 7;
    const int band = blockIdx.x >> 3;         // 0..31
    const int y0   = band * 2;
    const int pix0 = y0 * 64;
    const int wave = tid >> 6, lane = tid & 63;
    const int n = lane & 31, kj = lane >> 5;
    const int px = wave * 32 + n;             // block-local pixel 0..127
    const int pg = pix0 + px;                 // global pixel
    const int4 z4 = make_int4(0, 0, 0, 0);
    int phase = 0;

    float cre[48];
    #pragma unroll
    for (int i = 0; i < 48; i++) cre[i] = 0.f;

    // ================= encoder phase: h entirely in LDS recs [px][120] =====
    #pragma unroll 1
    for (int t = 0; t < T_; t++) {
        // x staging: 16 ch x 32 quads
        #pragma unroll
        for (int it = 0; it < 2; it++) {
            int i = tid + it * 256;
            int ch = i & 15, q = i >> 4;
            size_t base = ((size_t)(b * T_ + t) * CIN + ch) * HW + pix0 + q * 4;
            short v0, v1, v2, v3;
            if (f32) {
                float4 f = *(const float4*)((const float*)xe + base);
                v0 = f2bs(f.x); v1 = f2bs(f.y); v2 = f2bs(f.z); v3 = f2bs(f.w);
            } else {
                short4 sv = *(const short4*)((const short*)xe + base);
                v0 = sv.x; v1 = sv.y; v2 = sv.z; v3 = sv.w;
            }
            int sb = q * 4;
            lds[(sb + 0) * 120 + ch] = v0;
            lds[(sb + 1) * 120 + ch] = v1;
            lds[(sb + 2) * 120 + ch] = v2;
            lds[(sb + 3) * 120 + ch] = v3;
        }
        __syncthreads();

        f32x16 acc[12];
        #pragma unroll
        for (int m = 0; m < 12; m++)
            #pragma unroll
            for (int r = 0; r < 16; r++) acc[m][r] = 0.f;

        const short* rec = &lds[px * 120];
        if (t == 0) {
            bf16x8 bf = *(const bf16x8*)(rec + kj * 8);
            const short* a0 = EW + (size_t)lane * 8;
            #pragma unroll
            for (int mt = 0; mt < 12; mt++)
                acc[mt] = __builtin_amdgcn_mfma_f32_32x32x16_bf16(
                    *(const bf16x8*)(a0 + (size_t)mt * 512), bf, acc[mt], 0, 0, 0);
        } else {
            #pragma unroll
            for (int k0 = 0; k0 < 7; k0++) {
                bf16x8 bf = *(const bf16x8*)(rec + k0 * 16 + kj * 8);
                const short* a0 = EW + ((size_t)(k0 * 12) * 64 + lane) * 8;
                #pragma unroll
                for (int mt = 0; mt < 12; mt++)
                    acc[mt] = __builtin_amdgcn_mfma_f32_32x32x16_bf16(
                        *(const bf16x8*)(a0 + (size_t)mt * 512), bf, acc[mt], 0, 0, 0);
            }
        }
        __syncthreads();

        // epilogue: LSTM pointwise, c in regs, h -> own LDS rec (+16 offset)
        #pragma unroll
        for (int dt = 0; dt < 3; dt++) {
            #pragma unroll
            for (int r = 0; r < 16; r++) {
                int row = (r & 3) + 8 * (r >> 2) + 4 * kj;
                int d = dt * 32 + row;
                float fg = sigmf_(acc[dt][r]     + ebf[d]);
                float ig = sigmf_(acc[3 + dt][r] + ebi[d]);
                float gg = tanhf_(acc[6 + dt][r] + ebc[d]);
                float og = sigmf_(acc[9 + dt][r] + ebo[d]);
                int ci = dt * 16 + r;
                float cn = fmaf(cre[ci], fg, ig * gg);
                cre[ci] = cn;
                lds[px * 120 + 16 + d] = f2bs(tanhf_(cn) * og);
            }
        }
        __syncthreads();
        if (t == T_ - 1) {
            // publish final enc h to hPA (pixel-major 96-ch records)
            int px2 = tid >> 1, half = tid & 1;
            short* gdst = hPA + ((size_t)b * HW + pix0 + px2) * 96 + half * 48;
            const short* lsrc = &lds[px2 * 120 + 16 + half * 48];
            #pragma unroll
            for (int s2 = 0; s2 < 6; s2++)
                *(int4*)(gdst + s2 * 8) = *(const int4*)(lsrc + s2 * 8);
        }
    }
    phase++; gridbar(bar, phase * 256);

    // ================= decoder phase =====
    #pragma unroll 1
    for (int tt = 0; tt <= T_; tt++) {
        short* hR  = (tt & 1) ? hPB : hPA;    // h_{tt-1}
        short* hWr = (tt & 1) ? hPA : hPB;    // h_tt

        if (tt == 0) {
            // zero pass: edge slots + ch pads
            #pragma unroll 1
            for (int i = tid; i < 648; i += 256) {
                int addr_sh;
                if (i < 120) {
                    int r = i / 30, rem = i % 30;
                    int s = (rem / 15) * 65;
                    addr_sh = (r * 66 + s) * 120 + (rem % 15) * 8;
                } else {
                    int z = i - 120;
                    addr_sh = (z >> 1) * 120 + 104 + (z & 1) * 8;
                }
                *(int4*)(&lds[addr_sh]) = z4;
            }
            __syncthreads();
            // full h staging: 4 rows x 64 recs x 12 chunks, in 2 batches
            #pragma unroll
            for (int half_b = 0; half_b < 2; half_b++) {
                int4 tmp[6]; int ss2[6], jj2[6];
                #pragma unroll
                for (int i = 0; i < 6; i++) {
                    int c2 = tid + (half_b * 6 + i) * 256;
                    int s = c2 / 12, j = c2 - s * 12;
                    ss2[i] = s; jj2[i] = j;
                    int y = y0 - 1 + (s >> 6);
                    if ((unsigned)y < 64u)
                        tmp[i] = *(const int4*)(hR + ((size_t)b * HW + (size_t)y * 64 + (s & 63)) * 96 + j * 8);
                    else tmp[i] = z4;
                }
                #pragma unroll
                for (int i = 0; i < 6; i++) {
                    int s = ss2[i];
                    *(int4*)(&lds[((s >> 6) * 66 + 1 + (s & 63)) * 120 + 8 + jj2[i] * 8]) = tmp[i];
                }
            }
        } else {
            // halo staging only: rows y0-1 (slot-row 0) and y0+2 (slot-row 3)
            int4 tmp[6]; int ss2[6], jj2[6];
            #pragma unroll
            for (int i = 0; i < 6; i++) {
                int c2 = tid + i * 256;           // 0..1535
                int s = c2 / 12, j = c2 - s * 12; // s 0..127
                int hi = s >> 6;                  // 0 top, 1 bottom
                int y = hi ? (y0 + 2) : (y0 - 1);
                ss2[i] = hi * 3 * 66 + 1 + (s & 63);
                jj2[i] = j;
                if ((unsigned)y < 64u)
                    tmp[i] = *(const int4*)(hR + ((size_t)b * HW + (size_t)y * 64 + (s & 63)) * 96 + j * 8);
                else tmp[i] = z4;
            }
            #pragma unroll
            for (int i = 0; i < 6; i++)
                *(int4*)(&lds[ss2[i] * 120 + 8 + jj2[i] * 8]) = tmp[i];
        }
        // x staging: 4 rows x 8 ch x 16 quads (skip on final out-only pass)
        if (tt < T_) {
            #pragma unroll
            for (int it = 0; it < 2; it++) {
                int i = tid + it * 256;
                int ch = i & 7, q = (i >> 3) & 15, r = i >> 7;
                int y = y0 - 1 + r;
                short v0 = 0, v1 = 0, v2 = 0, v3 = 0;
                if ((unsigned)y < 64u) {
                    size_t base = ((size_t)(b * T_ + tt) * COUT + ch) * HW + y * 64 + q * 4;
                    if (f32) {
                        float4 f = *(const float4*)((const float*)xd + base);
                        v0 = f2bs(f.x); v1 = f2bs(f.y); v2 = f2bs(f.z); v3 = f2bs(f.w);
                    } else {
                        short4 sv = *(const short4*)((const short*)xd + base);
                        v0 = sv.x; v1 = sv.y; v2 = sv.z; v3 = sv.w;
                    }
                }
                int sb = r * 66 + 1 + q * 4;
                lds[(sb + 0) * 120 + ch] = v0;
                lds[(sb + 1) * 120 + ch] = v1;
                lds[(sb + 2) * 120 + ch] = v2;
                lds[(sb + 3) * 120 + ch] = v3;
            }
        }
        __syncthreads();

        const int rw = 1 + (wave >> 1);
        const int x0 = (wave & 1) * 32;

        f32x16 aF[9], aO[3], aOut;
        #pragma unroll
        for (int m = 0; m < 9; m++)
            #pragma unroll
            for (int r = 0; r < 16; r++) aF[m][r] = 0.f;
        #pragma unroll
        for (int m = 0; m < 3; m++)
            #pragma unroll
            for (int r = 0; r < 16; r++) aO[m][r] = 0.f;
        #pragma unroll
        for (int r = 0; r < 16; r++) aOut[r] = 0.f;

        // gates f,i,g: 9 taps x 7 ksteps (unrolled) x 9 m-tiles
        if (tt < T_) {
            #pragma unroll 1
            for (int tap = 0; tap < 9; tap++) {
                int dy = tap / 3 - 1, dx = tap - (tap / 3) * 3 - 1;
                const short* rec = &lds[((rw + dy) * 66 + 1 + x0 + n + dx) * 120];
                const short* ab = WtA + ((size_t)(tap * 7) * 12 * 64 + lane) * 8;
                #pragma unroll
                for (int k0 = 0; k0 < 7; k0++) {
                    bf16x8 bf = *(const bf16x8*)(rec + k0 * 16 + kj * 8);
                    const short* a0 = ab + (size_t)k0 * 12 * 64 * 8;
                    #pragma unroll
                    for (int mt = 0; mt < 9; mt++)
                        aF[mt] = __builtin_amdgcn_mfma_f32_32x32x16_bf16(
                            *(const bf16x8*)(a0 + (size_t)mt * 512), bf, aF[mt], 0, 0, 0);
                }
            }
            // o gate: center tap only, m-tiles 9..11 (unrolled)
            {
                const short* rec = &lds[(rw * 66 + 1 + x0 + n) * 120];
                const short* ab = WtA + ((size_t)(4 * 7) * 12 * 64 + lane) * 8;
                #pragma unroll
                for (int k0 = 0; k0 < 7; k0++) {
                    bf16x8 bf = *(const bf16x8*)(rec + k0 * 16 + kj * 8);
                    const short* a0 = ab + (size_t)k0 * 12 * 64 * 8 + 9 * 512;
                    #pragma unroll
                    for (int mt = 0; mt < 3; mt++)
                        aO[mt] = __builtin_amdgcn_mfma_f32_32x32x16_bf16(
                            *(const bf16x8*)(a0 + (size_t)mt * 512), bf, aO[mt], 0, 0, 0);
                }
            }
        }
        // out head on h_{tt-1}: separate clean loop (duplicate ds_reads, cheap)
        if (tt > 0) {
            #pragma unroll 1
            for (int tap = 0; tap < 9; tap++) {
                int dy = tap / 3 - 1, dx = tap - (tap / 3) * 3 - 1;
                const short* rec = &lds[((rw + dy) * 66 + 1 + x0 + n + dx) * 120];
                const short* kb = K2A + ((size_t)(tap * 7) * 64 + lane) * 8;
                #pragma unroll
                for (int k0 = 0; k0 < 7; k0++) {
                    bf16x8 bf = *(const bf16x8*)(rec + k0 * 16 + kj * 8);
                    aOut = __builtin_amdgcn_mfma_f32_32x32x16_bf16(
                        *(const bf16x8*)(kb + (size_t)k0 * 512), bf, aOut, 0, 0, 0);
                }
            }
        }
        __syncthreads();

        // fused out store for step tt-1 (C rows 0..7 = out channels)
        if (tt > 0) {
            #pragma unroll
            for (int r = 0; r < 4; r++) {
                int o = r + 4 * kj;
                float v = aOut[r] + b2[o];
                size_t oadr = ((size_t)(b * T_ + (tt - 1)) * COUT + o) * HW + pg;
                if (f32) ((float*)out)[oadr] = v;
                else     ((bf16*)out)[oadr] = __float2bfloat16(v);
            }
        }

        if (tt < T_) {
            // epilogue: LSTM pointwise, c in regs, h -> own staged recs
            #pragma unroll
            for (int dt = 0; dt < 3; dt++) {
                #pragma unroll
                for (int r = 0; r < 16; r++) {
                    int row = (r & 3) + 8 * (r >> 2) + 4 * kj;
                    int d = dt * 32 + row;
                    float fg = sigmf_(aF[dt][r]     + dbf[d]);
                    float ig = sigmf_(aF[3 + dt][r] + dbi[d]);
                    float gg = tanhf_(aF[6 + dt][r] + dbc[d]);
                    float og = sigmf_(aO[dt][r]     + dbo[d]);
                    int ci = dt * 16 + r;
                    float cn = fmaf(cre[ci], fg, ig * gg);
                    cre[ci] = cn;
                    float hv = tanhf_(cn) * og;
                    lds[((1 + (px >> 6)) * 66 + 1 + (px & 63)) * 120 + 8 + d] = f2bs(hv);
                }
            }
            __syncthreads();
            // publish own 2 rows to hWr (pixel-major records)
            int px2 = tid >> 1, half = tid & 1;
            short* gdst = hWr + ((size_t)b * HW + pix0 + px2) * 96 + half * 48;
            const short* lsrc = &lds[((1 + (px2 >> 6)) * 66 + 1 + (px2 & 63)) * 120 + 8 + half * 48];
            #pragma unroll
            for (int s2 = 0; s2 < 6; s2++)
                *(int4*)(gdst + s2 * 8) = *(const int4*)(lsrc + s2 * 8);
            phase++; gridbar(bar, phase * 256);
        }
        // no barrier after the final out-only pass (tt == T_)
    }
}

// ---------------------------------------------------------------------------
extern "C" void kernel_launch(void* const* d_in, const int* in_sizes, int n_in,
                              void* d_out, int out_size, void* d_ws, size_t ws_size,
                              hipStream_t stream)
{
    const void* enc_in = d_in[0];
    const void* dec_in = d_in[1];
    const void* eWf = d_in[2];  const void* ebf_ = d_in[3];
    const void* eWi = d_in[4];  const void* ebi_ = d_in[5];
    const void* eWc = d_in[6];  const void* ebc_ = d_in[7];
    const void* eWo = d_in[8];  const void* ebo_ = d_in[9];
    const void* dKf = d_in[10]; const void* dbf_ = d_in[11];
    const void* dKi = d_in[12]; const void* dbi_ = d_in[13];
    const void* dKc = d_in[14]; const void* dbc_ = d_in[15];
    const void* dWo = d_in[16]; const void* dbo_ = d_in[17];
    const void* oK  = d_in[18]; const void* obv = d_in[19];
    const void* lW  = d_in[20]; const void* lb  = d_in[21];

    int* flag = (int*)d_ws;
    int* bar  = (int*)d_ws + 8;
    float* ws = (float*)d_ws + 16;

    const int S = B_ * HD * HW;              // 3,145,728 state elems
    short* hPA = (short*)ws;                 // S shorts (pixel-major h)
    short* hPB = (short*)(ws + S / 2);       // S shorts
    float* Wbase = ws + S;
    float* Wf   = Wbase;
    float* Wi   = Wf + 10752;
    float* Wc   = Wi + 10752;
    float* Wo   = Wc + 10752;
    float* bfv  = Wo + 10752;
    float* biv  = bfv + 96;
    float* bcv  = biv + 96;
    float* bov  = bcv + 96;
    float* Kf   = bov + 96;
    float* Ki   = Kf + 89856;
    float* Kc   = Ki + 89856;
    float* dbfv = Kc + 89856;
    float* dbiv = dbfv + 96;
    float* dbcv = dbiv + 96;
    float* dWof = dbcv + 96;
    float* dbov = dWof + 9984;
    float* K2   = dbov + 96;
    float* b2   = K2 + 6912;
    short* WtA  = (short*)(b2 + 16);                  // 387,072 shorts
    short* EW   = (short*)(b2 + 16 + 193536);         // 43,008 shorts
    short* K2A  = (short*)(b2 + 16 + 193536 + 21504); // 32,256 shorts

    detect_k<<<dim3(1), dim3(64), 0, stream>>>(eWf, flag, bar);
    prep_k<<<dim3(1263), dim3(256), 0, stream>>>(
        eWf, eWi, eWc, eWo, ebf_, ebi_, ebc_, ebo_,
        dKf, dKi, dKc, dbf_, dbi_, dbc_, dWo, dbo_, Wbase, flag);
    combine_k<<<dim3(4), dim3(256), 0, stream>>>(oK, obv, lW, lb, K2, b2, flag);
    repack_mfma_k<<<dim3(189), dim3(256), 0, stream>>>(Kf, Ki, Kc, dWof, WtA);
    repack_enc_k<<<dim3(21), dim3(256), 0, stream>>>(Wf, Wi, Wc, Wo, EW);
    repack_k2a_k<<<dim3(16), dim3(256), 0, stream>>>(K2, K2A);

    net_k<<<dim3(256), dim3(256), 0, stream>>>(
        enc_in, dec_in, hPA, hPB, d_out,
        EW, WtA, K2A,
        bfv, biv, bcv, bov,
        dbfv, dbiv, dbcv, dbov,
        b2, flag, bar);
}

// Round 10
// 1911.144 us; speedup vs baseline: 1.3149x; 1.3149x over previous
//
#include <hip/hip_runtime.h>
#include <hip/hip_bf16.h>

#define B_   8
#define T_   12
#define CIN  16
#define HD   96
#define COUT 8
#define CE   112
#define CD   104
#define HW   4096
#define WIMG 64

typedef __hip_bfloat16 bf16;
typedef __attribute__((ext_vector_type(8))) short bf16x8;   // 8 bf16 (4 VGPRs)
typedef __attribute__((ext_vector_type(16))) float f32x16;  // MFMA 32x32 C/D

__device__ __forceinline__ float b2f(bf16 v) { return __bfloat162float(v); }
__device__ __forceinline__ float sigmf_(float x) { return 1.0f / (1.0f + __expf(-x)); }
__device__ __forceinline__ float tanhf_(float x) { return 2.0f / (1.0f + __expf(-2.0f * x)) - 1.0f; }

__device__ __forceinline__ float ldin(const void* p, long i, int f32) {
    return f32 ? ((const float*)p)[i] : b2f(((const bf16*)p)[i]);
}
__device__ __forceinline__ short f2bs(float v) {
    __hip_bfloat16 hv = __float2bfloat16(v);
    return *reinterpret_cast<short*>(&hv);
}

// ---------------------------------------------------------------------------
// manual grid barrier: monotonic arrival counter, device-scope atomics.
// ---------------------------------------------------------------------------
__device__ __forceinline__ void gridbar(int* bar, int target) {
    __syncthreads();
    if (threadIdx.x == 0) {
        __threadfence();
        atomicAdd(bar, 1);
        while (__hip_atomic_load(bar, __ATOMIC_RELAXED,
                                 __HIP_MEMORY_SCOPE_AGENT) < target)
            __builtin_amdgcn_s_sleep(2);
    }
    __syncthreads();
    __threadfence();
}

// ---------------------------------------------------------------------------
__global__ void detect_k(const void* w, int* flag, int* bar) {
    if (threadIdx.x == 0 && blockIdx.x == 0) {
        const unsigned short* u = (const unsigned short*)w;
        int bad = 0;
        for (int i = 0; i < 64; i++) {
            unsigned short v = u[i];
            unsigned e = (v >> 7) & 0xFF;
            if (!(v == 0 || (e >= 90 && e <= 128))) bad++;
        }
        *flag = (bad > 8) ? 1 : 0;
        *bar = 0;
    }
}

// ---------------------------------------------------------------------------
__global__ void prep_k(
    const void* p0, const void* p1, const void* p2, const void* p3,
    const void* p4, const void* p5, const void* p6, const void* p7,
    const void* p8, const void* p9, const void* p10, const void* p11,
    const void* p12, const void* p13, const void* p14, const void* p15,
    float* __restrict__ dst, const int* __restrict__ flag)
{
    const int f32 = *flag;
    const void* srcs[16] = {p0,p1,p2,p3,p4,p5,p6,p7,p8,p9,p10,p11,p12,p13,p14,p15};
    const int sizes[16] = {10752,10752,10752,10752, 96,96,96,96,
                           89856,89856,89856, 96,96,96, 9984, 96};
    int i = blockIdx.x * blockDim.x + threadIdx.x;
    float* d = dst;
    #pragma unroll 1
    for (int s = 0; s < 16; s++) {
        if (i < sizes[s]) { d[i] = ldin(srcs[s], i, f32); return; }
        i -= sizes[s];
        d += sizes[s];
    }
}

// ---------------------------------------------------------------------------
__global__ void combine_k(const void* __restrict__ oK, const void* __restrict__ obv,
                          const void* __restrict__ lW, const void* __restrict__ lb,
                          float* __restrict__ K2, float* __restrict__ b2,
                          const int* __restrict__ flag)
{
    const int f32 = *flag;
    int i = blockIdx.x * blockDim.x + threadIdx.x;
    if (i < HD * 9) {
        float acc[8] = {0,0,0,0,0,0,0,0};
        for (int cd = 0; cd < CD; cd++) {
            float kv = ldin(oK, cd * (HD * 9) + i, f32);
            #pragma unroll
            for (int o = 0; o < 8; o++)
                acc[o] = fmaf(kv, ldin(lW, cd * COUT + o, f32), acc[o]);
        }
        #pragma unroll
        for (int o = 0; o < 8; o++) K2[i * 8 + o] = acc[o];
    }
    if (i < COUT) {
        float a = ldin(lb, i, f32);
        for (int cd = 0; cd < CD; cd++)
            a = fmaf(ldin(obv, cd, f32), ldin(lW, cd * COUT + i, f32), a);
        b2[i] = a;
    }
}

// ---------------------------------------------------------------------------
// WtA[((tap*7 + k0)*12 + mt)*64 + lane]*8+j ; m=mt*32+(lane&31);
// gate=m/96 (f,i,g,o), d=m%96; ch = k0*16+(lane>>5)*8+j (0..111, >=104 pad)
// ---------------------------------------------------------------------------
__global__ void repack_mfma_k(const float* __restrict__ Kf, const float* __restrict__ Ki,
                              const float* __restrict__ Kc, const float* __restrict__ dWof,
                              short* __restrict__ WtA)
{
    int lin = blockIdx.x * 256 + threadIdx.x;
    if (lin >= 9 * 7 * 12 * 64) return;
    int lane = lin & 63;
    int rest = lin >> 6;
    int mt  = rest % 12;
    int k07 = rest / 12;
    int k0  = k07 % 7;
    int tap = k07 / 7;
    int m = mt * 32 + (lane & 31);
    int gate = m / 96, d = m % 96;
    int chb = k0 * 16 + (lane >> 5) * 8;
    #pragma unroll
    for (int j = 0; j < 8; j++) {
        int ch = chb + j;
        float v = 0.f;
        if (ch < 104) {
            if (gate == 0)      v = Kf[((size_t)d * CD + ch) * 9 + tap];
            else if (gate == 1) v = Ki[((size_t)d * CD + ch) * 9 + tap];
            else if (gate == 2) v = Kc[((size_t)d * CD + ch) * 9 + tap];
            else                v = (tap == 4) ? dWof[ch * HD + d] : 0.f;
        }
        WtA[(size_t)lin * 8 + j] = f2bs(v);
    }
}

// ---------------------------------------------------------------------------
__global__ void repack_enc_k(const float* __restrict__ Wf, const float* __restrict__ Wi,
                             const float* __restrict__ Wc, const float* __restrict__ Wo,
                             short* __restrict__ EW)
{
    int lin = blockIdx.x * 256 + threadIdx.x;
    if (lin >= 7 * 12 * 64) return;
    int lane = lin & 63;
    int rest = lin >> 6;
    int mt = rest % 12;
    int k0 = rest / 12;
    int m = mt * 32 + (lane & 31);
    int gate = m / 96, d = m % 96;
    int chb = k0 * 16 + (lane >> 5) * 8;
    const float* W = (gate == 0) ? Wf : (gate == 1) ? Wi : (gate == 2) ? Wc : Wo;
    #pragma unroll
    for (int j = 0; j < 8; j++)
        EW[(size_t)lin * 8 + j] = f2bs(W[(chb + j) * HD + d]);
}

// ---------------------------------------------------------------------------
__global__ void repack_k2a_k(const float* __restrict__ K2, short* __restrict__ K2A)
{
    int lin = blockIdx.x * 256 + threadIdx.x;
    if (lin >= 9 * 7 * 64) return;
    int lane = lin & 63;
    int rest = lin >> 6;
    int k0 = rest % 7;
    int tap = rest / 7;
    int m = lane & 31;
    int kb = k0 * 16 + (lane >> 5) * 8;
    #pragma unroll
    for (int j = 0; j < 8; j++) {
        int c = kb + j - 8;
        float v = (m < 8 && c >= 0 && c < 96) ? K2[(c * 9 + tap) * 8 + m] : 0.f;
        K2A[(size_t)lin * 8 + j] = f2bs(v);
    }
}

// ---------------------------------------------------------------------------
// persistent kernel, wave-specialized. grid 256 = 32 bands(2 rows) x 8 batch.
// block 512 = 8 waves, 2 waves/SIMD, <=256 VGPR (launch_bounds 512,2).
// waves 0..5: (dt = wave%3, npair = wave/3) -> f,i,g,o for d-slice dt*32..+31
//             over pixel-pair npair (64 px). Weight reads deduplicated.
// waves 6..7: fused out-head over pixel-pair (wave-6).
// c in registers (32 f32/thread, mapping identical in enc & dec phases).
// ---------------------------------------------------------------------------
__global__ void __launch_bounds__(512, 2) net_k(
    const void* __restrict__ xe, const void* __restrict__ xd,
    short* __restrict__ hPA, short* __restrict__ hPB,
    void* __restrict__ out,
    const short* __restrict__ EW, const short* __restrict__ WtA,
    const short* __restrict__ K2A,
    const float* __restrict__ ebf, const float* __restrict__ ebi,
    const float* __restrict__ ebc, const float* __restrict__ ebo,
    const float* __restrict__ dbf, const float* __restrict__ dbi,
    const float* __restrict__ dbc, const float* __restrict__ dbo,
    const float* __restrict__ b2, const int* __restrict__ flag,
    int* __restrict__ bar)
{
    __shared__ short lds[4 * 66 * 120];       // 63,360 B
    const int f32 = *flag;
    const int tid  = threadIdx.x;
    const int b    = blockIdx.x & 7;
    const int band = blockIdx.x >> 3;         // 0..31
    const int y0   = band * 2;
    const int pix0 = y0 * 64;
    const int wave = tid >> 6, lane = tid & 63;
    const int n = lane & 31, kj = lane >> 5;
    const bool is_gate = wave < 6;
    const int dt    = wave % 3;               // gate waves only
    const int npair = wave / 3;               // 0/1 for gate waves
    const int opair = wave - 6;               // 0/1 for out waves
    const int4 z4 = make_int4(0, 0, 0, 0);
    int phase = 0;

    float cre[32];
    #pragma unroll
    for (int i = 0; i < 32; i++) cre[i] = 0.f;

    // ================= encoder phase: h in LDS recs [px 0..127][120] =======
    #pragma unroll 1
    for (int t = 0; t < T_; t++) {
        // x staging: 16 ch x 32 quads = 512 tasks
        {
            int i = tid;
            int ch = i & 15, q = i >> 4;
            size_t base = ((size_t)(b * T_ + t) * CIN + ch) * HW + pix0 + q * 4;
            short v0, v1, v2, v3;
            if (f32) {
                float4 f = *(const float4*)((const float*)xe + base);
                v0 = f2bs(f.x); v1 = f2bs(f.y); v2 = f2bs(f.z); v3 = f2bs(f.w);
            } else {
                short4 sv = *(const short4*)((const short*)xe + base);
                v0 = sv.x; v1 = sv.y; v2 = sv.z; v3 = sv.w;
            }
            int sb = q * 4;
            lds[(sb + 0) * 120 + ch] = v0;
            lds[(sb + 1) * 120 + ch] = v1;
            lds[(sb + 2) * 120 + ch] = v2;
            lds[(sb + 3) * 120 + ch] = v3;
        }
        __syncthreads();

        f32x16 aE[8];
        if (is_gate) {
            #pragma unroll
            for (int m = 0; m < 8; m++)
                #pragma unroll
                for (int r = 0; r < 16; r++) aE[m][r] = 0.f;
            if (t == 0) {
                bf16x8 b0 = *(const bf16x8*)(&lds[((npair * 2 + 0) * 32 + n) * 120 + kj * 8]);
                bf16x8 b1 = *(const bf16x8*)(&lds[((npair * 2 + 1) * 32 + n) * 120 + kj * 8]);
                #pragma unroll
                for (int g = 0; g < 4; g++) {
                    bf16x8 av = *(const bf16x8*)(EW + ((size_t)(g * 3 + dt) * 64 + lane) * 8);
                    aE[g]     = __builtin_amdgcn_mfma_f32_32x32x16_bf16(av, b0, aE[g], 0, 0, 0);
                    aE[4 + g] = __builtin_amdgcn_mfma_f32_32x32x16_bf16(av, b1, aE[4 + g], 0, 0, 0);
                }
            } else {
                #pragma unroll 1
                for (int k0 = 0; k0 < 7; k0++) {
                    bf16x8 b0 = *(const bf16x8*)(&lds[((npair * 2 + 0) * 32 + n) * 120 + k0 * 16 + kj * 8]);
                    bf16x8 b1 = *(const bf16x8*)(&lds[((npair * 2 + 1) * 32 + n) * 120 + k0 * 16 + kj * 8]);
                    #pragma unroll
                    for (int g = 0; g < 4; g++) {
                        bf16x8 av = *(const bf16x8*)(EW + ((size_t)(k0 * 12 + g * 3 + dt) * 64 + lane) * 8);
                        aE[g]     = __builtin_amdgcn_mfma_f32_32x32x16_bf16(av, b0, aE[g], 0, 0, 0);
                        aE[4 + g] = __builtin_amdgcn_mfma_f32_32x32x16_bf16(av, b1, aE[4 + g], 0, 0, 0);
                    }
                }
            }
        }
        __syncthreads();

        if (is_gate) {
            #pragma unroll
            for (int pl = 0; pl < 2; pl++) {
                int px = (npair * 2 + pl) * 32 + n;
                #pragma unroll
                for (int r = 0; r < 16; r++) {
                    int row = (r & 3) + 8 * (r >> 2) + 4 * kj;
                    int d = dt * 32 + row;
                    float fg = sigmf_(aE[pl * 4 + 0][r] + ebf[d]);
                    float ig = sigmf_(aE[pl * 4 + 1][r] + ebi[d]);
                    float gg = tanhf_(aE[pl * 4 + 2][r] + ebc[d]);
                    float og = sigmf_(aE[pl * 4 + 3][r] + ebo[d]);
                    int ci = pl * 16 + r;
                    float cn = fmaf(cre[ci], fg, ig * gg);
                    cre[ci] = cn;
                    lds[px * 120 + 16 + d] = f2bs(tanhf_(cn) * og);
                }
            }
        }
        if (t == T_ - 1) {
            __syncthreads();
            int px2 = tid >> 2, qt = tid & 3;
            short* gdst = hPA + ((size_t)b * HW + pix0 + px2) * 96 + qt * 24;
            const short* lsrc = &lds[px2 * 120 + 16 + qt * 24];
            #pragma unroll
            for (int s2 = 0; s2 < 3; s2++)
                *(int4*)(gdst + s2 * 8) = *(const int4*)(lsrc + s2 * 8);
        }
    }
    phase++; gridbar(bar, phase * 256);

    // ================= decoder phase =====
    #pragma unroll 1
    for (int tt = 0; tt <= T_; tt++) {
        short* hR  = (tt & 1) ? hPB : hPA;    // h_{tt-1}
        short* hWr = (tt & 1) ? hPA : hPB;    // h_tt

        if (tt == 0) {
            // zero pass: edge slots + ch pads
            #pragma unroll 1
            for (int i = tid; i < 648; i += 512) {
                int addr_sh;
                if (i < 120) {
                    int r = i / 30, rem = i % 30;
                    int s = (rem / 15) * 65;
                    addr_sh = (r * 66 + s) * 120 + (rem % 15) * 8;
                } else {
                    int z = i - 120;
                    addr_sh = (z >> 1) * 120 + 104 + (z & 1) * 8;
                }
                *(int4*)(&lds[addr_sh]) = z4;
            }
            __syncthreads();
            // full h staging: 4 rows x 64 recs x 12 chunks = 3072
            #pragma unroll
            for (int i = 0; i < 6; i++) {
                int c2 = tid + i * 512;
                int s = c2 / 12, j = c2 - s * 12;
                int y = y0 - 1 + (s >> 6);
                int4 v = z4;
                if ((unsigned)y < 64u)
                    v = *(const int4*)(hR + ((size_t)b * HW + (size_t)y * 64 + (s & 63)) * 96 + j * 8);
                *(int4*)(&lds[((s >> 6) * 66 + 1 + (s & 63)) * 120 + 8 + j * 8]) = v;
            }
        } else {
            // halo staging: rows y0-1 (slot-row 0) and y0+2 (slot-row 3)
            #pragma unroll
            for (int i = 0; i < 3; i++) {
                int c2 = tid + i * 512;           // 0..1535
                int s = c2 / 12, j = c2 - s * 12; // s 0..127
                int hi = s >> 6;
                int y = hi ? (y0 + 2) : (y0 - 1);
                int4 v = z4;
                if ((unsigned)y < 64u)
                    v = *(const int4*)(hR + ((size_t)b * HW + (size_t)y * 64 + (s & 63)) * 96 + j * 8);
                *(int4*)(&lds[(hi * 3 * 66 + 1 + (s & 63)) * 120 + 8 + j * 8]) = v;
            }
        }
        // x staging: 4 rows x 8 ch x 16 quads = 512 tasks
        if (tt < T_) {
            int i = tid;
            int ch = i & 7, q = (i >> 3) & 15, r = i >> 7;
            int y = y0 - 1 + r;
            short v0 = 0, v1 = 0, v2 = 0, v3 = 0;
            if ((unsigned)y < 64u) {
                size_t base = ((size_t)(b * T_ + tt) * COUT + ch) * HW + y * 64 + q * 4;
                if (f32) {
                    float4 f = *(const float4*)((const float*)xd + base);
                    v0 = f2bs(f.x); v1 = f2bs(f.y); v2 = f2bs(f.z); v3 = f2bs(f.w);
                } else {
                    short4 sv = *(const short4*)((const short*)xd + base);
                    v0 = sv.x; v1 = sv.y; v2 = sv.z; v3 = sv.w;
                }
            }
            int sb = r * 66 + 1 + q * 4;
            lds[(sb + 0) * 120 + ch] = v0;
            lds[(sb + 1) * 120 + ch] = v1;
            lds[(sb + 2) * 120 + ch] = v2;
            lds[(sb + 3) * 120 + ch] = v3;
        }
        __syncthreads();

        f32x16 aG[6], aO2[2], aOut[2];
        if (is_gate && tt < T_) {
            #pragma unroll
            for (int m = 0; m < 6; m++)
                #pragma unroll
                for (int r = 0; r < 16; r++) aG[m][r] = 0.f;
            #pragma unroll
            for (int m = 0; m < 2; m++)
                #pragma unroll
                for (int r = 0; r < 16; r++) aO2[m][r] = 0.f;

            // gates f,i,g: 9 taps x 7 ksteps, only d-slice dt
            #pragma unroll 1
            for (int tap = 0; tap < 9; tap++) {
                int dy = tap / 3 - 1, dx = tap - (tap / 3) * 3 - 1;
                const short* r0 = &lds[((1 + npair + dy) * 66 + 1 + 0 * 32 + n + dx) * 120];
                const short* r1 = &lds[((1 + npair + dy) * 66 + 1 + 1 * 32 + n + dx) * 120];
                const short* ab = WtA + ((size_t)(tap * 7) * 12 * 64 + lane) * 8;
                #pragma unroll 1
                for (int k0 = 0; k0 < 7; k0++) {
                    bf16x8 b0 = *(const bf16x8*)(r0 + k0 * 16 + kj * 8);
                    bf16x8 b1 = *(const bf16x8*)(r1 + k0 * 16 + kj * 8);
                    const short* a0 = ab + (size_t)k0 * 12 * 64 * 8;
                    bf16x8 af_ = *(const bf16x8*)(a0 + (size_t)dt * 512);
                    bf16x8 ai_ = *(const bf16x8*)(a0 + (size_t)(3 + dt) * 512);
                    bf16x8 ag_ = *(const bf16x8*)(a0 + (size_t)(6 + dt) * 512);
                    aG[0] = __builtin_amdgcn_mfma_f32_32x32x16_bf16(af_, b0, aG[0], 0, 0, 0);
                    aG[3] = __builtin_amdgcn_mfma_f32_32x32x16_bf16(af_, b1, aG[3], 0, 0, 0);
                    aG[1] = __builtin_amdgcn_mfma_f32_32x32x16_bf16(ai_, b0, aG[1], 0, 0, 0);
                    aG[4] = __builtin_amdgcn_mfma_f32_32x32x16_bf16(ai_, b1, aG[4], 0, 0, 0);
                    aG[2] = __builtin_amdgcn_mfma_f32_32x32x16_bf16(ag_, b0, aG[2], 0, 0, 0);
                    aG[5] = __builtin_amdgcn_mfma_f32_32x32x16_bf16(ag_, b1, aG[5], 0, 0, 0);
                }
            }
            // o gate: center tap only
            {
                const short* r0 = &lds[((1 + npair) * 66 + 1 + 0 * 32 + n) * 120];
                const short* r1 = &lds[((1 + npair) * 66 + 1 + 1 * 32 + n) * 120];
                const short* ab = WtA + ((size_t)(4 * 7) * 12 * 64 + lane) * 8;
                #pragma unroll 1
                for (int k0 = 0; k0 < 7; k0++) {
                    bf16x8 b0 = *(const bf16x8*)(r0 + k0 * 16 + kj * 8);
                    bf16x8 b1 = *(const bf16x8*)(r1 + k0 * 16 + kj * 8);
                    bf16x8 ao_ = *(const bf16x8*)(ab + (size_t)k0 * 12 * 64 * 8 + (size_t)(9 + dt) * 512);
                    aO2[0] = __builtin_amdgcn_mfma_f32_32x32x16_bf16(ao_, b0, aO2[0], 0, 0, 0);
                    aO2[1] = __builtin_amdgcn_mfma_f32_32x32x16_bf16(ao_, b1, aO2[1], 0, 0, 0);
                }
            }
        }
        if (!is_gate && tt > 0) {
            #pragma unroll
            for (int m = 0; m < 2; m++)
                #pragma unroll
                for (int r = 0; r < 16; r++) aOut[m][r] = 0.f;
            #pragma unroll 1
            for (int tap = 0; tap < 9; tap++) {
                int dy = tap / 3 - 1, dx = tap - (tap / 3) * 3 - 1;
                const short* r0 = &lds[((1 + opair + dy) * 66 + 1 + 0 * 32 + n + dx) * 120];
                const short* r1 = &lds[((1 + opair + dy) * 66 + 1 + 1 * 32 + n + dx) * 120];
                const short* kb = K2A + ((size_t)(tap * 7) * 64 + lane) * 8;
                #pragma unroll 1
                for (int k0 = 0; k0 < 7; k0++) {
                    bf16x8 b0 = *(const bf16x8*)(r0 + k0 * 16 + kj * 8);
                    bf16x8 b1 = *(const bf16x8*)(r1 + k0 * 16 + kj * 8);
                    bf16x8 kv = *(const bf16x8*)(kb + (size_t)k0 * 512);
                    aOut[0] = __builtin_amdgcn_mfma_f32_32x32x16_bf16(kv, b0, aOut[0], 0, 0, 0);
                    aOut[1] = __builtin_amdgcn_mfma_f32_32x32x16_bf16(kv, b1, aOut[1], 0, 0, 0);
                }
            }
        }
        __syncthreads();

        // out store for step tt-1 (C rows 0..7 = out channels)
        if (!is_gate && tt > 0) {
            #pragma unroll
            for (int pl = 0; pl < 2; pl++) {
                int p = opair * 2 + pl;
                int pgp = (y0 + (p >> 1)) * 64 + (p & 1) * 32 + n;
                #pragma unroll
                for (int r = 0; r < 4; r++) {
                    int o = r + 4 * kj;
                    float v = aOut[pl][r] + b2[o];
                    size_t oadr = ((size_t)(b * T_ + (tt - 1)) * COUT + o) * HW + pgp;
                    if (f32) ((float*)out)[oadr] = v;
                    else     ((bf16*)out)[oadr] = __float2bfloat16(v);
                }
            }
        }
        // epilogue: LSTM pointwise, c in regs, h -> own staged recs
        if (is_gate && tt < T_) {
            #pragma unroll
            for (int pl = 0; pl < 2; pl++) {
                #pragma unroll
                for (int r = 0; r < 16; r++) {
                    int row = (r & 3) + 8 * (r >> 2) + 4 * kj;
                    int d = dt * 32 + row;
                    float fg = sigmf_(aG[pl * 3 + 0][r] + dbf[d]);
                    float ig = sigmf_(aG[pl * 3 + 1][r] + dbi[d]);
                    float gg = tanhf_(aG[pl * 3 + 2][r] + dbc[d]);
                    float og = sigmf_(aO2[pl][r] + dbo[d]);
                    int ci = pl * 16 + r;
                    float cn = fmaf(cre[ci], fg, ig * gg);
                    cre[ci] = cn;
                    float hv = tanhf_(cn) * og;
                    lds[((1 + npair) * 66 + 1 + pl * 32 + n) * 120 + 8 + d] = f2bs(hv);
                }
            }
        }
        if (tt < T_) {
            __syncthreads();
            // publish own 2 rows (128 recs) to hWr
            int px2 = tid >> 2, qt = tid & 3;
            short* gdst = hWr + ((size_t)b * HW + pix0 + px2) * 96 + qt * 24;
            const short* lsrc = &lds[((1 + (px2 >> 6)) * 66 + 1 + (px2 & 63)) * 120 + 8 + qt * 24];
            #pragma unroll
            for (int s2 = 0; s2 < 3; s2++)
                *(int4*)(gdst + s2 * 8) = *(const int4*)(lsrc + s2 * 8);
            phase++; gridbar(bar, phase * 256);
        }
    }
}

// ---------------------------------------------------------------------------
extern "C" void kernel_launch(void* const* d_in, const int* in_sizes, int n_in,
                              void* d_out, int out_size, void* d_ws, size_t ws_size,
                              hipStream_t stream)
{
    const void* enc_in = d_in[0];
    const void* dec_in = d_in[1];
    const void* eWf = d_in[2];  const void* ebf_ = d_in[3];
    const void* eWi = d_in[4];  const void* ebi_ = d_in[5];
    const void* eWc = d_in[6];  const void* ebc_ = d_in[7];
    const void* eWo = d_in[8];  const void* ebo_ = d_in[9];
    const void* dKf = d_in[10]; const void* dbf_ = d_in[11];
    const void* dKi = d_in[12]; const void* dbi_ = d_in[13];
    const void* dKc = d_in[14]; const void* dbc_ = d_in[15];
    const void* dWo = d_in[16]; const void* dbo_ = d_in[17];
    const void* oK  = d_in[18]; const void* obv = d_in[19];
    const void* lW  = d_in[20]; const void* lb  = d_in[21];

    int* flag = (int*)d_ws;
    int* bar  = (int*)d_ws + 8;
    float* ws = (float*)d_ws + 16;

    const int S = B_ * HD * HW;              // 3,145,728 state elems
    short* hPA = (short*)ws;                 // S shorts (pixel-major h)
    short* hPB = (short*)(ws + S / 2);       // S shorts
    float* Wbase = ws + S;
    float* Wf   = Wbase;
    float* Wi   = Wf + 10752;
    float* Wc   = Wi + 10752;
    float* Wo   = Wc + 10752;
    float* bfv  = Wo + 10752;
    float* biv  = bfv + 96;
    float* bcv  = biv + 96;
    float* bov  = bcv + 96;
    float* Kf   = bov + 96;
    float* Ki   = Kf + 89856;
    float* Kc   = Ki + 89856;
    float* dbfv = Kc + 89856;
    float* dbiv = dbfv + 96;
    float* dbcv = dbiv + 96;
    float* dWof = dbcv + 96;
    float* dbov = dWof + 9984;
    float* K2   = dbov + 96;
    float* b2   = K2 + 6912;
    short* WtA  = (short*)(b2 + 16);                  // 387,072 shorts
    short* EW   = (short*)(b2 + 16 + 193536);         // 43,008 shorts
    short* K2A  = (short*)(b2 + 16 + 193536 + 21504); // 32,256 shorts

    detect_k<<<dim3(1), dim3(64), 0, stream>>>(eWf, flag, bar);
    prep_k<<<dim3(1263), dim3(256), 0, stream>>>(
        eWf, eWi, eWc, eWo, ebf_, ebi_, ebc_, ebo_,
        dKf, dKi, dKc, dbf_, dbi_, dbc_, dWo, dbo_, Wbase, flag);
    combine_k<<<dim3(4), dim3(256), 0, stream>>>(oK, obv, lW, lb, K2, b2, flag);
    repack_mfma_k<<<dim3(189), dim3(256), 0, stream>>>(Kf, Ki, Kc, dWof, WtA);
    repack_enc_k<<<dim3(21), dim3(256), 0, stream>>>(Wf, Wi, Wc, Wo, EW);
    repack_k2a_k<<<dim3(16), dim3(256), 0, stream>>>(K2, K2A);

    net_k<<<dim3(256), dim3(512), 0, stream>>>(
        enc_in, dec_in, hPA, hPB, d_out,
        EW, WtA, K2A,
        bfv, biv, bcv, bov,
        dbfv, dbiv, dbcv, dbov,
        b2, flag, bar);
}